// Round 3
// baseline (1361.488 us; speedup 1.0000x reference)
//
#include <hip/hip_runtime.h>
#include <stdint.h>

typedef __attribute__((ext_vector_type(8))) short bf16x8;
typedef __attribute__((ext_vector_type(4))) float f32x4;
typedef __attribute__((ext_vector_type(4))) unsigned short us4;
typedef unsigned short u16;

#define DEVI static __device__ __forceinline__

#define Bb 4
#define Tt 4096
#define Cch 512
#define DFFd 2048
#define Mrows (Bb*Tt)

DEVI u16 f2bf(float f){
  union{float f;unsigned u;} v; v.f = f;
  unsigned r = v.u + 0x7FFFu + ((v.u >> 16) & 1u);
  return (u16)(r >> 16);
}
DEVI float bf2f(u16 h){
  union{unsigned u;float f;} v; v.u = (unsigned)h << 16; return v.f;
}

DEVI void gload16(const void* g, void* l){
  __builtin_amdgcn_global_load_lds((const __attribute__((address_space(1))) unsigned int*)g,
                                   (__attribute__((address_space(3))) unsigned int*)l, 16, 0, 0);
}

// ---------------- split cast f32 -> (hi, lo) bf16 ----------------
__global__ void k_split_cast(const float* __restrict__ in, u16* __restrict__ hi,
                             u16* __restrict__ lo, int n){
  int i = (blockIdx.x * blockDim.x + threadIdx.x) * 4;
  if(i < n){
    float4 f = *(const float4*)(in + i);
    us4 h, l;
    h.x = f2bf(f.x); l.x = f2bf(f.x - bf2f(h.x));
    h.y = f2bf(f.y); l.y = f2bf(f.y - bf2f(h.y));
    h.z = f2bf(f.z); l.z = f2bf(f.z - bf2f(h.z));
    h.w = f2bf(f.w); l.w = f2bf(f.w - bf2f(h.w));
    *(us4*)(hi + i) = h; *(us4*)(lo + i) = l;
  }
}

// ------------- transpose-cast f32 -> bf16 (plain) -------------
__global__ void k_transpose_f32_bf16(const float* __restrict__ in, u16* __restrict__ out,
                                     int inStride, int outStride){
  __shared__ float tile[32][33];
  int c0 = blockIdx.x * 32, r0 = blockIdx.y * 32;
  int tx = threadIdx.x, ty = threadIdx.y; // (32,8)
  #pragma unroll
  for(int j = 0; j < 4; j++)
    tile[ty + 8*j][tx] = in[(size_t)(r0 + ty + 8*j) * inStride + c0 + tx];
  __syncthreads();
  #pragma unroll
  for(int j = 0; j < 4; j++)
    out[(size_t)(c0 + ty + 8*j) * outStride + r0 + tx] = f2bf(tile[tx][ty + 8*j]);
}

// ------------- transpose-cast f32 -> (hi,lo) bf16 -------------
__global__ void k_transpose_split(const float* __restrict__ in, u16* __restrict__ oh,
                                  u16* __restrict__ ol, int inStride, int outStride){
  __shared__ float tile[32][33];
  int c0 = blockIdx.x * 32, r0 = blockIdx.y * 32;
  int tx = threadIdx.x, ty = threadIdx.y;
  #pragma unroll
  for(int j = 0; j < 4; j++)
    tile[ty + 8*j][tx] = in[(size_t)(r0 + ty + 8*j) * inStride + c0 + tx];
  __syncthreads();
  #pragma unroll
  for(int j = 0; j < 4; j++){
    float x = tile[tx][ty + 8*j];
    u16 h = f2bf(x);
    size_t o = (size_t)(c0 + ty + 8*j) * outStride + r0 + tx;
    oh[o] = h; ol[o] = f2bf(x - bf2f(h));
  }
}

// ------------- V transpose (bf16): Vt[b][c][t] = V[b*T+t][c] -------------
__global__ void k_transpose_v(const u16* __restrict__ V, u16* __restrict__ Vt){
  __shared__ u16 tile[32][33];
  int b = blockIdx.z;
  const u16* in = V + (size_t)b * Tt * Cch;
  u16* out = Vt + (size_t)b * Cch * Tt;
  int c0 = blockIdx.x * 32, r0 = blockIdx.y * 32;
  int tx = threadIdx.x, ty = threadIdx.y;
  #pragma unroll
  for(int j = 0; j < 4; j++)
    tile[ty + 8*j][tx] = in[(size_t)(r0 + ty + 8*j) * Cch + c0 + tx];
  __syncthreads();
  #pragma unroll
  for(int j = 0; j < 4; j++)
    out[(size_t)(c0 + ty + 8*j) * Tt + r0 + tx] = tile[tx][ty + 8*j];
}

// ---------------- split-precision GEMM core ----------------
DEVI void core_split(const u16* __restrict__ Ah, const u16* __restrict__ Al,
                     const u16* __restrict__ Bh, const u16* __restrict__ Bl,
                     int lda, int ldb, int K,
                     u16* Ash, u16* Asl, u16* Bsh, u16* Bsl,
                     f32x4 (&acc)[4][4]){
  const int t = threadIdx.x;
  const int lane = t & 63, w = t >> 6;
  const int l15 = lane & 15, l4 = lane >> 4;
  const int wr = (w >> 1) * 64, wc = (w & 1) * 64;
  for(int kt = 0; kt < K; kt += 32){
    __syncthreads();
    #pragma unroll
    for(int i = 0; i < 2; i++){
      int row = i*64 + (t >> 2);
      int ce  = (t & 3) * 8;
      size_t ao = (size_t)row * lda + kt + ce;
      size_t bo = (size_t)row * ldb + kt + ce;
      gload16(Ah + ao, (char*)Ash + i*4096 + t*16);
      gload16(Al + ao, (char*)Asl + i*4096 + t*16);
      gload16(Bh + bo, (char*)Bsh + i*4096 + t*16);
      gload16(Bl + bo, (char*)Bsl + i*4096 + t*16);
    }
    __syncthreads();
    bf16x8 ah[4], al[4], bh[4], bl[4];
    #pragma unroll
    for(int mi = 0; mi < 4; mi++){
      ah[mi] = *(const bf16x8*)((const char*)Ash + (wr + mi*16 + l15)*64 + l4*16);
      al[mi] = *(const bf16x8*)((const char*)Asl + (wr + mi*16 + l15)*64 + l4*16);
    }
    #pragma unroll
    for(int ni = 0; ni < 4; ni++){
      bh[ni] = *(const bf16x8*)((const char*)Bsh + (wc + ni*16 + l15)*64 + l4*16);
      bl[ni] = *(const bf16x8*)((const char*)Bsl + (wc + ni*16 + l15)*64 + l4*16);
    }
    #pragma unroll
    for(int mi = 0; mi < 4; mi++)
      #pragma unroll
      for(int ni = 0; ni < 4; ni++){
        acc[mi][ni] = __builtin_amdgcn_mfma_f32_16x16x32_bf16(ah[mi], bh[ni], acc[mi][ni], 0, 0, 0);
        acc[mi][ni] = __builtin_amdgcn_mfma_f32_16x16x32_bf16(ah[mi], bl[ni], acc[mi][ni], 0, 0, 0);
        acc[mi][ni] = __builtin_amdgcn_mfma_f32_16x16x32_bf16(al[mi], bh[ni], acc[mi][ni], 0, 0, 0);
      }
  }
}

// ---------------- QK projection, split precision, hi/lo output [M][1024] ----------------
__global__ __launch_bounds__(256) void k_qk_split(const u16* __restrict__ Xh, const u16* __restrict__ Xl,
                                                  const u16* __restrict__ Wh, const u16* __restrict__ Wl,
                                                  u16* __restrict__ Qh, u16* __restrict__ Ql){
  __shared__ u16 Ash[4096], Asl[4096], Bsh[4096], Bsl[4096];
  const int bm = blockIdx.x * 128, bn = blockIdx.y * 128;
  f32x4 acc[4][4] = {};
  core_split(Xh + (size_t)bm*512, Xl + (size_t)bm*512,
             Wh + (size_t)bn*512, Wl + (size_t)bn*512,
             512, 512, 512, Ash, Asl, Bsh, Bsl, acc);
  const int t = threadIdx.x, lane = t & 63, w = t >> 6;
  const int l15 = lane & 15, l4 = lane >> 4;
  const int wr = (w >> 1) * 64, wc = (w & 1) * 64;
  #pragma unroll
  for(int mi = 0; mi < 4; mi++)
    #pragma unroll
    for(int ni = 0; ni < 4; ni++){
      int col = bn + wc + ni*16 + l15;
      #pragma unroll
      for(int r = 0; r < 4; r++){
        int row = bm + wr + mi*16 + l4*4 + r;
        float v = acc[mi][ni][r];
        u16 h = f2bf(v);
        size_t o = (size_t)row * 1024 + col;
        Qh[o] = h; Ql[o] = f2bf(v - bf2f(h));
      }
    }
}

// ---------------- plain GEMM core ----------------
DEVI void core_plain(const u16* __restrict__ A, const u16* __restrict__ B,
                     int lda, int ldb, int K, u16* As, u16* Bs, f32x4 (&acc)[4][4]){
  const int t = threadIdx.x;
  const int lane = t & 63, w = t >> 6;
  const int l15 = lane & 15, l4 = lane >> 4;
  const int wr = (w >> 1) * 64, wc = (w & 1) * 64;
  for(int kt = 0; kt < K; kt += 32){
    __syncthreads();
    #pragma unroll
    for(int i = 0; i < 2; i++){
      int row = i*64 + (t >> 2);
      int ce  = (t & 3) * 8;
      gload16(A + (size_t)row * lda + kt + ce, (char*)As + i*4096 + t*16);
      gload16(B + (size_t)row * ldb + kt + ce, (char*)Bs + i*4096 + t*16);
    }
    __syncthreads();
    bf16x8 af[4], bfr[4];
    #pragma unroll
    for(int mi = 0; mi < 4; mi++)
      af[mi] = *(const bf16x8*)((const char*)As + (wr + mi*16 + l15)*64 + l4*16);
    #pragma unroll
    for(int ni = 0; ni < 4; ni++)
      bfr[ni] = *(const bf16x8*)((const char*)Bs + (wc + ni*16 + l15)*64 + l4*16);
    #pragma unroll
    for(int mi = 0; mi < 4; mi++)
      #pragma unroll
      for(int ni = 0; ni < 4; ni++)
        acc[mi][ni] = __builtin_amdgcn_mfma_f32_16x16x32_bf16(af[mi], bfr[ni], acc[mi][ni], 0, 0, 0);
  }
}

// ---------------- plain GEMM with epilogues ----------------
// EPI: 0 = store bf16 ; 1 = +bias, relu, store bf16 ; 2 = +bias, store f32
template<int EPI>
__global__ __launch_bounds__(256) void k_gemm(const u16* __restrict__ A,
                                              const u16* __restrict__ Bt,
                                              void* __restrict__ Cp,
                                              const float* __restrict__ bias,
                                              int K, int ldc){
  __shared__ u16 As[4096], Bs[4096];
  const int bm = blockIdx.x * 128, bn = blockIdx.y * 128;
  f32x4 acc[4][4] = {};
  core_plain(A + (size_t)bm*K, Bt + (size_t)bn*K, K, K, K, As, Bs, acc);
  const int t = threadIdx.x, lane = t & 63, w = t >> 6;
  const int l15 = lane & 15, l4 = lane >> 4;
  const int wr = (w >> 1) * 64, wc = (w & 1) * 64;
  #pragma unroll
  for(int mi = 0; mi < 4; mi++)
    #pragma unroll
    for(int ni = 0; ni < 4; ni++){
      int col = bn + wc + ni*16 + l15;
      float bv = (EPI > 0) ? bias[col] : 0.f;
      #pragma unroll
      for(int r = 0; r < 4; r++){
        int row = bm + wr + mi*16 + l4*4 + r;
        float v = acc[mi][ni][r] + bv;
        if(EPI == 1){ v = v > 0.f ? v : 0.f; ((u16*)Cp)[(size_t)row * ldc + col] = f2bf(v); }
        else if(EPI == 2){ ((float*)Cp)[(size_t)row * ldc + col] = v; }
        else { ((u16*)Cp)[(size_t)row * ldc + col] = f2bf(v); }
      }
    }
}

// ---------------- Flash attention, split-precision QK^T, QB=KVB=32, 2 waves ----------------
__global__ __launch_bounds__(128, 1) void k_attn(const u16* __restrict__ QKh,
                                                 const u16* __restrict__ QKl,
                                                 const u16* __restrict__ Vt,
                                                 u16* __restrict__ NV){
  __shared__ u16 Ksh[32 * 512];  // 32KB
  __shared__ u16 Ksl[32 * 512];  // 32KB
  __shared__ u16 Vs[512 * 32];   // 32KB
  __shared__ u16 Ps[2][16 * 40];

  int bx = blockIdx.x;
  int qt = (bx & 1) ? (127 - (bx >> 1)) : (bx >> 1);  // balance causal work
  int b  = blockIdx.y;
  int t = threadIdx.x, lane = t & 63, w = t >> 6;
  int l15 = lane & 15, l4 = lane >> 4;
  int qbase = qt * 32;
  size_t rowb = (size_t)b * Tt;

  bf16x8 qfh[16], qfl[16];
  {
    const u16* qph = QKh + (rowb + qbase + w*16 + l15) * 1024;
    const u16* qpl = QKl + (rowb + qbase + w*16 + l15) * 1024;
    #pragma unroll
    for(int s = 0; s < 16; s++){
      qfh[s] = *(const bf16x8*)(qph + s*32 + l4*8);
      qfl[s] = *(const bf16x8*)(qpl + s*32 + l4*8);
    }
  }

  f32x4 Ov[32];
  #pragma unroll
  for(int nt = 0; nt < 32; nt++) Ov[nt] = (f32x4){0.f,0.f,0.f,0.f};
  float mrow[4], lrow[4];
  #pragma unroll
  for(int r = 0; r < 4; r++){ mrow[r] = -__builtin_inff(); lrow[r] = 0.f; }

  const int ntiles = qt + 1;
  for(int it = 0; it < ntiles; ++it){
    int kv0 = it * 32;
    __syncthreads();
    #pragma unroll
    for(int i = 0; i < 16; i++){
      size_t krow = (rowb + kv0 + i*2 + w) * 1024 + 512 + lane*8;
      gload16(QKh + krow, (char*)Ksh + i*2048 + t*16);
      gload16(QKl + krow, (char*)Ksl + i*2048 + t*16);
      const u16* gv = Vt + ((size_t)b*Cch + i*32 + (t >> 2)) * Tt + kv0 + (t & 3)*8;
      gload16(gv, (char*)Vs + i*2048 + t*16);
    }
    __syncthreads();

    // S = Q K^T  split precision (2 column tiles of 16)
    f32x4 sf[2];
    sf[0] = (f32x4){0.f,0.f,0.f,0.f};
    sf[1] = (f32x4){0.f,0.f,0.f,0.f};
    #pragma unroll
    for(int ct = 0; ct < 2; ct++){
      #pragma unroll
      for(int s = 0; s < 16; s++){
        bf16x8 kfh = *(const bf16x8*)((const char*)Ksh + (ct*16 + l15)*1024 + s*64 + l4*16);
        bf16x8 kfl = *(const bf16x8*)((const char*)Ksl + (ct*16 + l15)*1024 + s*64 + l4*16);
        sf[ct] = __builtin_amdgcn_mfma_f32_16x16x32_bf16(qfh[s], kfh, sf[ct], 0, 0, 0);
        sf[ct] = __builtin_amdgcn_mfma_f32_16x16x32_bf16(qfh[s], kfl, sf[ct], 0, 0, 0);
        sf[ct] = __builtin_amdgcn_mfma_f32_16x16x32_bf16(qfl[s], kfh, sf[ct], 0, 0, 0);
      }
    }

    // causal mask + online softmax
    int qg = qbase + w*16 + l4*4;
    int kg0 = kv0 + l15, kg1 = kv0 + 16 + l15;
    float p0[4], p1[4], scl[4];
    #pragma unroll
    for(int r = 0; r < 4; r++){
      float s0 = sf[0][r]; if(kg0 > qg + r) s0 = -__builtin_inff();
      float s1 = sf[1][r]; if(kg1 > qg + r) s1 = -__builtin_inff();
      float tm = fmaxf(s0, s1);
      tm = fmaxf(tm, __shfl_xor(tm, 1));
      tm = fmaxf(tm, __shfl_xor(tm, 2));
      tm = fmaxf(tm, __shfl_xor(tm, 4));
      tm = fmaxf(tm, __shfl_xor(tm, 8));
      float m2 = fmaxf(mrow[r], tm);
      float sc = __expf(mrow[r] - m2);
      p0[r] = __expf(s0 - m2);
      p1[r] = __expf(s1 - m2);
      float psum = p0[r] + p1[r];
      psum += __shfl_xor(psum, 1);
      psum += __shfl_xor(psum, 2);
      psum += __shfl_xor(psum, 4);
      psum += __shfl_xor(psum, 8);
      lrow[r] = lrow[r] * sc + psum;
      mrow[r] = m2; scl[r] = sc;
    }
    #pragma unroll
    for(int nt = 0; nt < 32; nt++){
      #pragma unroll
      for(int r = 0; r < 4; r++) Ov[nt][r] *= scl[r];
    }

    // P -> LDS -> A-operand layout
    u16* Pw = &Ps[w][0];
    #pragma unroll
    for(int r = 0; r < 4; r++){
      Pw[(l4*4 + r)*40 + l15]      = f2bf(p0[r]);
      Pw[(l4*4 + r)*40 + 16 + l15] = f2bf(p1[r]);
    }
    bf16x8 paf = *(const bf16x8*)(Pw + l15*40 + l4*8);

    // O += P V
    #pragma unroll
    for(int nt = 0; nt < 32; nt++){
      bf16x8 vf = *(const bf16x8*)((const char*)Vs + (nt*16 + l15)*64 + l4*16);
      Ov[nt] = __builtin_amdgcn_mfma_f32_16x16x32_bf16(paf, vf, Ov[nt], 0, 0, 0);
    }
  }

  u16* op = NV + (rowb + qbase + w*16) * Cch;
  #pragma unroll
  for(int nt = 0; nt < 32; nt++){
    #pragma unroll
    for(int r = 0; r < 4; r++){
      float v = Ov[nt][r] / lrow[r];
      op[(size_t)(l4*4 + r) * Cch + nt*16 + l15] = f2bf(v);
    }
  }
}

// ---------------- launch ----------------
extern "C" void kernel_launch(void* const* d_in, const int* in_sizes, int n_in,
                              void* d_out, int out_size, void* d_ws, size_t ws_size,
                              hipStream_t stream){
  (void)in_sizes; (void)n_in; (void)out_size; (void)ws_size;
  const float* X  = (const float*)d_in[0];
  const float* Wq = (const float*)d_in[1];
  const float* Wk = (const float*)d_in[2];
  const float* Wv = (const float*)d_in[3];
  const float* W1 = (const float*)d_in[4];
  const float* b1 = (const float*)d_in[5];
  const float* W2 = (const float*)d_in[6];
  const float* b2 = (const float*)d_in[7];
  float* out = (float*)d_out;

  // workspace layout (byte offsets), total 150.5 MB; H aliases {Xh,Xl,QKl}
  const size_t MB = 1024ull*1024ull;
  char* ws = (char*)d_ws;
  u16* Xh   = (u16*)(ws + 0);        // 16MB, dead after V-proj
  u16* Xl   = (u16*)(ws + 16*MB);    // 16MB, dead after QK-proj
  u16* QKl  = (u16*)(ws + 32*MB);    // 32MB, dead after attn
  u16* H    = (u16*)(ws + 0);        // 64MB, alias: FFN stage only
  u16* QKh  = (u16*)(ws + 64*MB);    // 32MB
  u16* V    = (u16*)(ws + 96*MB);    // 16MB
  u16* Vt   = (u16*)(ws + 112*MB);   // 16MB
  u16* NV   = (u16*)(ws + 128*MB);   // 16MB
  u16* Wqkh = (u16*)(ws + 144*MB);   // 1MB
  u16* Wqkl = (u16*)(ws + 145*MB);   // 1MB
  u16* Wvt  = (u16*)(ws + 146*MB);   // 0.5MB
  u16* W1t  = (u16*)(ws + 147*MB);   // 2MB
  u16* W2t  = (u16*)(ws + 149*MB);   // 2MB

  dim3 tb(32, 8);

  // 1. split-cast X
  k_split_cast<<<Mrows*Cch/4/256, 256, 0, stream>>>(X, Xh, Xl, Mrows*Cch);

  // 2. weight transposes (Wq/Wk split, Wv/W1/W2 plain)
  k_transpose_split<<<dim3(16,16), tb, 0, stream>>>(Wq, Wqkh,           Wqkl,           512, 512);
  k_transpose_split<<<dim3(16,16), tb, 0, stream>>>(Wk, Wqkh + 512*512, Wqkl + 512*512, 512, 512);
  k_transpose_f32_bf16<<<dim3(16,16), tb, 0, stream>>>(Wv, Wvt, 512, 512);
  k_transpose_f32_bf16<<<dim3(64,16), tb, 0, stream>>>(W1, W1t, 2048, 512);
  k_transpose_f32_bf16<<<dim3(16,64), tb, 0, stream>>>(W2, W2t, 512, 2048);

  // 3. QK projection (split), V projection (plain)
  k_qk_split<<<dim3(128, 8), 256, 0, stream>>>(Xh, Xl, Wqkh, Wqkl, QKh, QKl);
  k_gemm<0><<<dim3(128, 4), 256, 0, stream>>>(Xh, Wvt, V, nullptr, Cch, Cch);

  // 4. V transpose
  k_transpose_v<<<dim3(16, 128, Bb), tb, 0, stream>>>(V, Vt);

  // 5. fused causal flash attention (split QK^T)
  k_attn<<<dim3(128, Bb), 128, 0, stream>>>(QKh, QKl, Vt, NV);

  // 6. FFN
  k_gemm<1><<<dim3(128, 16), 256, 0, stream>>>(NV, W1t, H,   b1, Cch,  DFFd);
  k_gemm<2><<<dim3(128, 4),  256, 0, stream>>>(H,  W2t, out, b2, DFFd, Cch);
}